// Round 13
// baseline (63.710 us; speedup 1.0000x reference)
//
#include <hip/hip_runtime.h>
#include <float.h>
#include <math.h>

#pragma clang fp contract(off)

#define R 8192
#define NCLS 80
#define SC 81          // scores row width (K+1)
#define TOPK_N 100
#define SCORE_THRESH 0.05f
#define NMS_THRESH 0.5f

// workspace layout (bytes)
#define BOXC_OFF   0            // float4[R]                 131072
#define ENT_OFF    131072       // u64 entries[8000]         64000 -> 195072
#define CCNT_OFF   195072       // int ccnt[80]              320   -> 195392
#define DONE_OFF   195456       // uint done-counter         (pad) -> 195584
#define COUNTS_OFF 195584       // u32 counts[80][256]       81920 -> 277504
#define CKEYS_OFF  277760       // u64 ckeys[80][8192]       5242880
#define NENT       (NCLS * TOPK_N)   // 8000

__device__ __forceinline__ bool finitef(float x) {
    return fabsf(x) <= FLT_MAX;   // false for NaN and +-inf
}

// key packing: (score_bits << 13) | (8191 - r)  -> u64 desc == (score desc, r asc)
__device__ __forceinline__ unsigned long long pack_key(float sc, int r) {
    return ((unsigned long long)__float_as_uint(sc) << 13) |
           (unsigned long long)(8191 - r);
}

// ------------- kernel A: prep (clip, validity) + fused per-class compaction -------
#define PREP_ROWS 32
#define PREP_THREADS 256

__global__ __launch_bounds__(PREP_THREADS) void prep_kernel(
    const float* __restrict__ boxes,
    const float* __restrict__ scores,
    const int* __restrict__ imh,
    const int* __restrict__ imw,
    float4* __restrict__ boxes_c,
    unsigned long long* __restrict__ entries,
    unsigned long long* __restrict__ ckeys,
    unsigned int* __restrict__ counts,
    unsigned int* __restrict__ done) {
    __shared__ float s_sc[PREP_ROWS * SC];                  // 10368 B
    __shared__ int s_vld[PREP_ROWS];
    __shared__ int s_ccnt[NCLS];
    __shared__ unsigned long long s_ckey[NCLS][PREP_ROWS];  // 20480 B

    const int tid = threadIdx.x;
    const int blk = blockIdx.x;
    const int r0 = blk * PREP_ROWS;

    if (blk == 0 && tid == 0) *done = 0u;
    {   // zero the 8000 entry slots across the first 32 blocks
        int i = blk * PREP_THREADS + tid;
        if (i < NENT) entries[i] = 0ull;
    }
    if (tid < PREP_ROWS) s_vld[tid] = 1;
    if (tid < NCLS) s_ccnt[tid] = 0;
    __syncthreads();

    // coalesced float4 load of 32 rows x 81 scores
    const float4* src4 = (const float4*)(scores + (size_t)r0 * SC);
    float4* dst4 = (float4*)s_sc;
    for (int idx = tid; idx < PREP_ROWS * SC / 4; idx += PREP_THREADS) {
        float4 v = src4[idx];
        dst4[idx] = v;
        int e = idx * 4;
        if (!finitef(v.x)) atomicAnd(&s_vld[(e + 0) / SC], 0);
        if (!finitef(v.y)) atomicAnd(&s_vld[(e + 1) / SC], 0);
        if (!finitef(v.z)) atomicAnd(&s_vld[(e + 2) / SC], 0);
        if (!finitef(v.w)) atomicAnd(&s_vld[(e + 3) / SC], 0);
    }

    // boxes: 32 coalesced float4 loads, clip, store
    if (tid < PREP_ROWS) {
        float4 b = ((const float4*)boxes)[r0 + tid];
        bool bok = finitef(b.x) && finitef(b.y) && finitef(b.z) && finitef(b.w);
        float w = (float)(*imw), h = (float)(*imh);
        float4 bc;
        bc.x = fminf(fmaxf(b.x, 0.f), w);
        bc.y = fminf(fmaxf(b.y, 0.f), h);
        bc.z = fminf(fmaxf(b.z, 0.f), w);
        bc.w = fminf(fmaxf(b.w, 0.f), h);
        boxes_c[r0 + tid] = bc;
        if (!bok) atomicAnd(&s_vld[tid], 0);
    }
    __syncthreads();

    // per-class compaction within this block's 32 rows (block-owned segments)
    for (int idx = tid; idx < NCLS * PREP_ROWS; idx += PREP_THREADS) {
        int k = idx >> 5, rr = idx & 31;
        float sc = s_sc[rr * SC + k];
        if (sc > SCORE_THRESH && s_vld[rr]) {
            int p = atomicAdd(&s_ccnt[k], 1);
            s_ckey[k][p] = pack_key(sc, r0 + rr);
        }
    }
    __syncthreads();

    if (tid < NCLS) counts[(size_t)tid * 256 + blk] = (unsigned int)s_ccnt[tid];
    for (int idx = tid; idx < NCLS * PREP_ROWS; idx += PREP_THREADS) {
        int k = idx >> 5, m = idx & 31;
        if (m < s_ccnt[k])
            ckeys[((size_t)k << 13) + (blk << 5) + m] = s_ckey[k][m];
    }
}

// ------------- kernel B: gather + sort + greedy NMS + last-block topk -------------
#define NMS_THREADS 512
#define KMAX 192
#define PF 512
#define TIECAP 512

template <int U>
__device__ __forceinline__ void rank_sort_inplace(unsigned long long* s_key,
                                                  int cnt, int tid) {
    unsigned long long kv[U];
    int rk[U];
#pragma unroll
    for (int m = 0; m < U; ++m) {
        int i = tid + m * NMS_THREADS;
        kv[m] = (i < cnt) ? s_key[i] : 0ull;
        rk[m] = 0;
    }
    {
        const ulonglong2* kp2 = (const ulonglong2*)s_key;
        const int ng = (cnt + 7) >> 3;   // caller padded s_key[cnt..cnt+7] = 0
        for (int g = 0; g < ng; ++g) {
            ulonglong2 a = kp2[g * 4 + 0];
            ulonglong2 b = kp2[g * 4 + 1];
            ulonglong2 c = kp2[g * 4 + 2];
            ulonglong2 d = kp2[g * 4 + 3];
#pragma unroll
            for (int m = 0; m < U; ++m) {
                unsigned long long kk = kv[m];
                rk[m] += (int)(a.x > kk) + (int)(a.y > kk)
                       + (int)(b.x > kk) + (int)(b.y > kk)
                       + (int)(c.x > kk) + (int)(c.y > kk)
                       + (int)(d.x > kk) + (int)(d.y > kk);
            }
        }
    }
    __syncthreads();
#pragma unroll
    for (int m = 0; m < U; ++m) {
        int i = tid + m * NMS_THREADS;
        if (i < cnt) s_key[rk[m]] = kv[m];
    }
}

__device__ __forceinline__ void sort_keys(unsigned long long* s_key, int cnt, int tid) {
    if (cnt <= 512) {
        rank_sort_inplace<1>(s_key, cnt, tid);
    } else if (cnt <= 1024) {
        rank_sort_inplace<2>(s_key, cnt, tid);
    } else if (cnt <= 2048) {
        rank_sort_inplace<4>(s_key, cnt, tid);
    } else if (cnt <= 4096) {
        rank_sort_inplace<8>(s_key, cnt, tid);
    } else {
        int npad = 8192;
        for (int i = cnt + tid; i < npad; i += NMS_THREADS) s_key[i] = 0ull;
        __syncthreads();
        for (int kk = 2; kk <= npad; kk <<= 1) {
            for (int j = kk >> 1; j > 0; j >>= 1) {
                for (int i = tid; i < npad; i += NMS_THREADS) {
                    int ixj = i ^ j;
                    if (ixj > i) {
                        unsigned long long a = s_key[i], b = s_key[ixj];
                        bool ascending = ((i & kk) == 0);
                        if ((b > a) == ascending) { s_key[i] = b; s_key[ixj] = a; }
                    }
                }
                __syncthreads();
            }
        }
    }
    __syncthreads();
}

__device__ __forceinline__ float iou_soa(float cx, float cy, float cz, float cw,
                                         float car,
                                         float ox, float oy, float oz, float ow,
                                         float oa) {
    float ltx = fmaxf(cx, ox), lty = fmaxf(cy, oy);
    float rbx = fminf(cz, oz), rby = fminf(cw, ow);
    float iw = fmaxf(rbx - ltx, 0.f), ih = fmaxf(rby - lty, 0.f);
    float inter = iw * ih;
    float uni = car + oa - inter + 1e-9f;
    return inter / uni;
}

__global__ __launch_bounds__(NMS_THREADS) void nms_topk_kernel(
    const unsigned long long* __restrict__ ckeys,
    const unsigned int* __restrict__ counts,
    const float4* __restrict__ boxes_c,
    unsigned long long* __restrict__ entries,
    int* __restrict__ ccnt,
    unsigned int* __restrict__ done,
    float* __restrict__ out) {
    __shared__ unsigned long long s_key[R + 8];   // 64 KB; topk reuses as keys+hist
    __shared__ float s_cbx[PF], s_cby[PF], s_cbz[PF], s_cbw[PF], s_ca[PF];
    __shared__ float kbx[KMAX], kby[KMAX], kbz[KMAX], kbw[KMAX], ka[KMAX];
    __shared__ float sgx[64], sgy[64], sgz[64], sgw[64], sga[64];
    __shared__ unsigned int s_part[8][64];
    __shared__ unsigned int s_sup1[8][64];
    __shared__ unsigned int s_cntb[256];
    __shared__ unsigned int s_pref[256];
    __shared__ unsigned int s_wsum[4];
    __shared__ int s_kept;
    __shared__ int s_last;
    // topk small state
    __shared__ unsigned int wt[4];
    __shared__ unsigned int s_binr[2];
    __shared__ unsigned int selk[TOPK_N];
    __shared__ int          selp[TOPK_N];
    __shared__ unsigned int fkey[TOPK_N];
    __shared__ int          fpos[TOPK_N];
    __shared__ int          tiepos[TIECAP];
    __shared__ unsigned int a_gt, a_tie;
    __shared__ int s_M;

    const int tid = threadIdx.x;
    const int k = blockIdx.x;
    const int lane = tid & 63;
    const int wv = tid >> 6;

    if (tid == 0) s_kept = 0;
    for (int i = tid; i < KMAX; i += NMS_THREADS) {
        kbx[i] = 0.f; kby[i] = 0.f; kbz[i] = 0.f; kbw[i] = 0.f; ka[i] = 0.f;
    }
    __syncthreads();

    // ---- counts row + prefix scan (first 4 waves) ----
    unsigned int v = 0, cb_ = 0;
    if (tid < 256) {
        cb_ = counts[((size_t)k << 8) + tid];
        s_cntb[tid] = cb_;
        v = cb_;
#pragma unroll
        for (int d = 1; d < 64; d <<= 1) {
            unsigned int o = __shfl_up(v, d);
            if (lane >= d) v += o;
        }
        if (lane == 63) s_wsum[wv] = v;
    }
    __syncthreads();
    if (tid < 256) {
        unsigned int offs = 0;
        for (int w2 = 0; w2 < wv; ++w2) offs += s_wsum[w2];
        s_pref[tid] = offs + v - cb_;
    }
    __syncthreads();
    const int cnt = (int)(s_wsum[0] + s_wsum[1] + s_wsum[2] + s_wsum[3]);

    if (cnt > 0) {
        // ---- gather keys from 256 block-segments into LDS ----
        const unsigned long long* ck = ckeys + ((size_t)k << 13);
        for (int idx = tid; idx < 256 * PREP_ROWS; idx += NMS_THREADS) {
            int b = idx >> 5, m = idx & 31;
            if ((unsigned)m < s_cntb[b]) s_key[s_pref[b] + m] = ck[idx];
        }
        __syncthreads();
        if (tid < 8) s_key[cnt + tid] = 0ull;   // pad for vectorized scan
        __syncthreads();

        sort_keys(s_key, cnt, tid);

        // ---- SoA prefetch of first min(cnt,PF) sorted candidate boxes ----
        const int pfn = cnt < PF ? cnt : PF;
        for (int i = tid; i < pfn; i += NMS_THREADS) {
            int b = 8191 - (int)(s_key[i] & 8191ull);
            float4 cb = boxes_c[b];
            s_cbx[i] = cb.x; s_cby[i] = cb.y; s_cbz[i] = cb.z; s_cbw[i] = cb.w;
            s_ca[i] = fmaxf(cb.z - cb.x, 0.f) * fmaxf(cb.w - cb.y, 0.f);
        }
        __syncthreads();

        // ---- greedy NMS over 64-candidate chunks ----
        const int nchunks = (cnt + 63) >> 6;
        for (int c = 0; c < nchunks; ++c) {
            const int kept0 = s_kept;
            if (kept0 >= TOPK_N) break;     // uniform
            const int jbase = c << 6;
            const int j = jbase + lane;
            const bool incand = (j < cnt);
            const bool pf = (jbase < PF);

            if (!pf) {
                if (tid < 64) {
                    float4 cb = make_float4(0.f, 0.f, 0.f, 0.f);
                    if (incand) {
                        int b = 8191 - (int)(s_key[j] & 8191ull);
                        cb = boxes_c[b];
                    }
                    sgx[lane] = cb.x; sgy[lane] = cb.y;
                    sgz[lane] = cb.z; sgw[lane] = cb.w;
                    sga[lane] = fmaxf(cb.z - cb.x, 0.f) * fmaxf(cb.w - cb.y, 0.f);
                }
                __syncthreads();
            }

            const float* BX = pf ? &s_cbx[jbase] : sgx;
            const float* BY = pf ? &s_cby[jbase] : sgy;
            const float* BZ = pf ? &s_cbz[jbase] : sgz;
            const float* BW = pf ? &s_cbw[jbase] : sgw;
            const float* BA = pf ? &s_ca[jbase] : sga;

            float cx = 0.f, cy = 0.f, cz = 0.f, cw = 0.f, car = 0.f;
            if (incand) {
                cx = BX[lane]; cy = BY[lane]; cz = BZ[lane]; cw = BW[lane];
                car = BA[lane];
            }

            {   // kept-list test + intra-chunk adjacency (8-wave parallel)
                const int L4 = (((kept0 + 7) >> 3) + 3) & ~3;
                const int t0 = wv * L4;
                unsigned int sup = 0u;
                for (int t = t0; t < t0 + L4; t += 4) {
                    float4 xs = *(const float4*)&kbx[t];
                    float4 ys = *(const float4*)&kby[t];
                    float4 zs = *(const float4*)&kbz[t];
                    float4 ws = *(const float4*)&kbw[t];
                    float4 as = *(const float4*)&ka[t];
                    if (iou_soa(cx, cy, cz, cw, car, xs.x, ys.x, zs.x, ws.x, as.x) > NMS_THRESH) sup = 1u;
                    if (iou_soa(cx, cy, cz, cw, car, xs.y, ys.y, zs.y, ws.y, as.y) > NMS_THRESH) sup = 1u;
                    if (iou_soa(cx, cy, cz, cw, car, xs.z, ys.z, zs.z, ws.z, as.z) > NMS_THRESH) sup = 1u;
                    if (iou_soa(cx, cy, cz, cw, car, xs.w, ys.w, zs.w, ws.w, as.w) > NMS_THRESH) sup = 1u;
                }
                s_sup1[wv][lane] = sup;

                const int i0 = wv << 3;
                float4 xa = *(const float4*)&BX[i0], xb = *(const float4*)&BX[i0 + 4];
                float4 ya = *(const float4*)&BY[i0], yb = *(const float4*)&BY[i0 + 4];
                float4 za = *(const float4*)&BZ[i0], zb = *(const float4*)&BZ[i0 + 4];
                float4 wa = *(const float4*)&BW[i0], wb = *(const float4*)&BW[i0 + 4];
                float4 aa = *(const float4*)&BA[i0], ab = *(const float4*)&BA[i0 + 4];
                float X[8] = {xa.x, xa.y, xa.z, xa.w, xb.x, xb.y, xb.z, xb.w};
                float Y[8] = {ya.x, ya.y, ya.z, ya.w, yb.x, yb.y, yb.z, yb.w};
                float Z[8] = {za.x, za.y, za.z, za.w, zb.x, zb.y, zb.z, zb.w};
                float W[8] = {wa.x, wa.y, wa.z, wa.w, wb.x, wb.y, wb.z, wb.w};
                float A[8] = {aa.x, aa.y, aa.z, aa.w, ab.x, ab.y, ab.z, ab.w};
                unsigned int pm = 0u;
#pragma unroll
                for (int ii = 0; ii < 8; ++ii) {
                    int i = i0 + ii;
                    if (i != lane &&
                        iou_soa(cx, cy, cz, cw, car, X[ii], Y[ii], Z[ii], W[ii], A[ii]) > NMS_THRESH)
                        pm |= 1u << ii;
                }
                s_part[wv][lane] = pm;
            }
            __syncthreads();

            if (tid < 64) {   // wave 0: bitmask greedy resolve
                unsigned int sup1u = 0u;
                unsigned long long supmask = 0ull;
#pragma unroll
                for (int w2 = 0; w2 < 8; ++w2) {
                    sup1u |= s_sup1[w2][lane];
                    supmask |= (unsigned long long)s_part[w2][lane] << (w2 * 8);
                }
                bool alive0 = incand && !sup1u;
                unsigned long long av = __ballot(alive0);
                unsigned long long kept = 0ull;
#pragma unroll
                for (int l2 = 0; l2 < 64; ++l2) {
                    unsigned long long m = __shfl(supmask, l2);
                    if (((av >> l2) & 1ull) && !(m & kept)) kept |= 1ull << l2;
                }
                if ((kept >> lane) & 1ull) {
                    int pos = kept0 + (int)__popcll(kept & ((1ull << lane) - 1ull));
                    if (pos < KMAX) {
                        kbx[pos] = cx; kby[pos] = cy; kbz[pos] = cz; kbw[pos] = cw;
                        ka[pos] = car;
                    }
                    if (pos < TOPK_N) {
                        unsigned long long kv = s_key[j];
                        int bidx = 8191 - (int)(kv & 8191ull);
                        entries[k * TOPK_N + pos] =
                            ((unsigned long long)(unsigned int)(k * R + bidx) << 32) |
                            (kv >> 13);
                    }
                }
                if (lane == 0) s_kept = kept0 + (int)__popcll(kept);
            }
            __syncthreads();
        }
    }

    if (tid == 0) {
        int kf = s_kept;
        ccnt[k] = kf < TOPK_N ? kf : TOPK_N;
    }

    // ---- completion protocol: last finished block performs global topk ----
    __threadfence();
    if (tid == 0) {
        unsigned int old = atomicAdd(done, 1u);
        s_last = (old == NCLS - 1) ? 1 : 0;
    }
    __syncthreads();
    if (!s_last) return;
    __threadfence();

    // =================== topk phase (runs in the last block) ===================
    unsigned int* t_keys = (unsigned int*)s_key;                       // 32000 B
    uint4*        t_keys4 = (uint4*)s_key;
    unsigned int* hist = (unsigned int*)((char*)s_key + 32768);        // 16384 B
    const unsigned int* e32 = (const unsigned int*)entries;

    {   // coalesced: entries low words -> LDS
        const ulonglong2* e2 = (const ulonglong2*)entries;
        for (int idx = tid; idx < NENT / 2; idx += NMS_THREADS) {
            ulonglong2 vv = e2[idx];
            t_keys[2 * idx + 0] = (unsigned int)vv.x;
            t_keys[2 * idx + 1] = (unsigned int)vv.y;
        }
    }
    if (tid == 0) { a_gt = 0u; a_tie = 0u; s_M = 0; }
    if (tid < TOPK_N) { fkey[tid] = 0u; fpos[tid] = 0; }
    __syncthreads();
    if (tid < NCLS) atomicAdd(&s_M, ccnt[tid]);
    __syncthreads();
    const int M = s_M;

    unsigned int T = 0u;
    unsigned int needed_ties = 0u;
    if (M >= TOPK_N) {
        unsigned int r = TOPK_N;
        unsigned int P = 0x0Fu;       // keys are floats in (0.05,1]: bits 31..26
        int hi = 26;
        const int nbits_arr[3] = {8, 8, 10};
        for (int lvl = 0; lvl < 3; ++lvl) {
            const int nbits = nbits_arr[lvl];
            const int nb = 1 << nbits;
            const int sh = hi - nbits;
            for (int j = tid; j < 4 * 1024; j += NMS_THREADS) hist[j] = 0u;
            __syncthreads();
            unsigned int* hw = &hist[(wv & 3) * 1024];
#pragma unroll
            for (int i = 0; i < 4; ++i) {
                int idx4 = i * NMS_THREADS + tid;
                if (idx4 < NENT / 4) {
                    uint4 kv4 = t_keys4[idx4];
                    if ((kv4.x >> hi) == P) atomicAdd(&hw[(kv4.x >> sh) & (nb - 1)], 1u);
                    if ((kv4.y >> hi) == P) atomicAdd(&hw[(kv4.y >> sh) & (nb - 1)], 1u);
                    if ((kv4.z >> hi) == P) atomicAdd(&hw[(kv4.z >> sh) & (nb - 1)], 1u);
                    if ((kv4.w >> hi) == P) atomicAdd(&hw[(kv4.w >> sh) & (nb - 1)], 1u);
                }
            }
            __syncthreads();
            const int G = nb >> 8;
            unsigned int g = 0u, S = 0u, Sown = 0u;
            if (tid < 256) {
                for (int b = 0; b < G; ++b) {
                    int bin = tid * G + b;
                    g += hist[bin] + hist[1024 + bin] + hist[2048 + bin] + hist[3072 + bin];
                }
                S = g;
                for (int off = 1; off < 64; off <<= 1) {
                    unsigned int v2 = __shfl_down(S, off);
                    if (lane + off < 64) S += v2;
                }
                if (lane == 0) wt[wv] = S;
            }
            __syncthreads();
            if (tid < 256) {
                unsigned int above_w = 0u;
                for (int w2 = wv + 1; w2 < 4; ++w2) above_w += wt[w2];
                Sown = S + above_w;
                unsigned int above = Sown - g;
                if (above < r && r <= Sown) {
                    unsigned int cum = above;
                    for (int b = G - 1; b >= 0; --b) {
                        int bin = tid * G + b;
                        unsigned int tb = hist[bin] + hist[1024 + bin] +
                                          hist[2048 + bin] + hist[3072 + bin];
                        cum += tb;
                        if (cum >= r) {
                            s_binr[0] = (unsigned int)bin;
                            s_binr[1] = r - (cum - tb);
                            break;
                        }
                    }
                }
            }
            __syncthreads();
            P = (P << nbits) | s_binr[0];
            r = s_binr[1];
            hi = sh;
            __syncthreads();
        }
        T = P;
        needed_ties = r;
    }
    __syncthreads();

    const unsigned int Teff = (M >= TOPK_N) ? T : 0u;
    if (M > 0) {
#pragma unroll
        for (int i = 0; i < 4; ++i) {
            int idx4 = i * NMS_THREADS + tid;
            if (idx4 < NENT / 4) {
                uint4 kv4 = t_keys4[idx4];
                unsigned int kvs[4] = {kv4.x, kv4.y, kv4.z, kv4.w};
#pragma unroll
                for (int c = 0; c < 4; ++c) {
                    unsigned int kv = kvs[c];
                    int pos = 4 * idx4 + c;
                    if (kv > Teff) {
                        unsigned int p = atomicAdd(&a_gt, 1u);
                        selk[p] = kv; selp[p] = pos;
                    } else if (M >= TOPK_N && kv == Teff) {
                        unsigned int q = atomicAdd(&a_tie, 1u);
                        if (q < TIECAP) tiepos[q] = pos;
                    }
                }
            }
        }
    }
    __syncthreads();
    const unsigned int ngt = a_gt;
    if (M >= TOPK_N && needed_ties > 0u) {
        unsigned int ntie = a_tie < TIECAP ? a_tie : TIECAP;
        for (unsigned int j = tid; j < ntie; j += NMS_THREADS) {
            int pj = tiepos[j];
            unsigned int rnk = 0u;
            for (unsigned int j2 = 0; j2 < ntie; ++j2) rnk += (tiepos[j2] < pj);
            if (rnk < needed_ties) { selk[ngt + rnk] = T; selp[ngt + rnk] = pj; }
        }
    }
    __syncthreads();

    const int SELN = (M >= TOPK_N) ? TOPK_N : M;
    if (tid < SELN) {
        unsigned int kk = selk[tid];
        int pp = selp[tid];
        unsigned int rnk = 0u;
        for (int j = 0; j < SELN; ++j) {
            unsigned int kj = selk[j];
            int pj = selp[j];
            rnk += (kj > kk) || (kj == kk && pj < pp);
        }
        fkey[rnk] = kk;
        fpos[rnk] = pp;
    }
    __syncthreads();

    if (tid < TOPK_N) {
        bool dv = (tid < SELN);
        int pos = fpos[tid];
        float s = __uint_as_float(fkey[tid]);
        int flat = dv ? (int)e32[2 * pos + 1] : 0;
        int r2 = flat & (R - 1);
        int kc = flat >> 13;
        float4 bb = dv ? boxes_c[r2] : make_float4(0.f, 0.f, 0.f, 0.f);
        out[tid * 4 + 0] = bb.x;
        out[tid * 4 + 1] = bb.y;
        out[tid * 4 + 2] = bb.z;
        out[tid * 4 + 3] = bb.w;
        out[400 + tid] = dv ? s : 0.f;
        out[500 + tid] = dv ? (float)kc : -1.f;
        out[600 + tid] = dv ? (float)r2 : -1.f;
    }
}

extern "C" void kernel_launch(void* const* d_in, const int* in_sizes, int n_in,
                              void* d_out, int out_size, void* d_ws, size_t ws_size,
                              hipStream_t stream) {
    const float* boxes  = (const float*)d_in[0];
    const float* scores = (const float*)d_in[1];
    const int*   imh    = (const int*)d_in[2];
    const int*   imw    = (const int*)d_in[3];

    char* ws = (char*)d_ws;
    float4*             boxes_c = (float4*)(ws + BOXC_OFF);
    unsigned long long* entries = (unsigned long long*)(ws + ENT_OFF);
    int*                ccnt    = (int*)(ws + CCNT_OFF);
    unsigned int*       done    = (unsigned int*)(ws + DONE_OFF);
    unsigned int*       counts  = (unsigned int*)(ws + COUNTS_OFF);
    unsigned long long* ckeys   = (unsigned long long*)(ws + CKEYS_OFF);

    prep_kernel<<<R / PREP_ROWS, PREP_THREADS, 0, stream>>>(
        boxes, scores, imh, imw, boxes_c, entries, ckeys, counts, done);
    nms_topk_kernel<<<NCLS, NMS_THREADS, 0, stream>>>(
        ckeys, counts, boxes_c, entries, ccnt, done, (float*)d_out);
}

// Round 14
// 40.802 us; speedup vs baseline: 1.5615x; 1.5615x over previous
//
#include <hip/hip_runtime.h>
#include <float.h>
#include <math.h>

#pragma clang fp contract(off)

#define R 8192
#define NCLS 80
#define SC 81          // scores row width (K+1)
#define TOPK_N 100
#define SCORE_THRESH 0.05f
#define NMS_THRESH 0.5f

// workspace layout (bytes)
#define BOXC_OFF   0            // float4[R]              131072
#define AREA_OFF   131072       // float[R] (<0 => row invalid)
#define ENT_OFF    163840       // u64 entries[8000] = 64000 -> 227840
#define CCNT_OFF   227840       // int ccnt[80] (pad to 228352)
#define ST_OFF     228352       // float scores_T[NCLS][R] = 2621440
#define NENT       (NCLS * TOPK_N)   // 8000

__device__ __forceinline__ bool finitef(float x) {
    return fabsf(x) <= FLT_MAX;   // false for NaN and +-inf
}

// key packing: (score_bits << 13) | (8191 - r)  -> u64 desc == (score desc, r asc)
__device__ __forceinline__ unsigned long long pack_key(float sc, int r) {
    return ((unsigned long long)__float_as_uint(sc) << 13) |
           (unsigned long long)(8191 - r);
}

// ---------------- kernel A: coalesced prep (clip, validity, transpose) -------------
#define PREP_ROWS 32
#define PREP_THREADS 256

__global__ __launch_bounds__(PREP_THREADS) void prep_kernel(
    const float* __restrict__ boxes,
    const float* __restrict__ scores,
    const int* __restrict__ imh,
    const int* __restrict__ imw,
    float4* __restrict__ boxes_c,
    float* __restrict__ area,
    unsigned long long* __restrict__ entries,
    float* __restrict__ scores_t,
    int do_t) {
    __shared__ float s_sc[PREP_ROWS * SC];   // 10368 B
    __shared__ int s_vld[PREP_ROWS];

    const int tid = threadIdx.x;
    const int blk = blockIdx.x;
    const int r0 = blk * PREP_ROWS;

    {   // zero the 8000 entry slots across the first 32 blocks
        int i = blk * PREP_THREADS + tid;
        if (i < NENT) entries[i] = 0ull;
    }
    if (tid < PREP_ROWS) s_vld[tid] = 1;
    __syncthreads();

    const float4* src4 = (const float4*)(scores + (size_t)r0 * SC);
    float4* dst4 = (float4*)s_sc;
    for (int idx = tid; idx < PREP_ROWS * SC / 4; idx += PREP_THREADS) {
        float4 v = src4[idx];
        dst4[idx] = v;
        int e = idx * 4;
        if (!finitef(v.x)) atomicAnd(&s_vld[(e + 0) / SC], 0);
        if (!finitef(v.y)) atomicAnd(&s_vld[(e + 1) / SC], 0);
        if (!finitef(v.z)) atomicAnd(&s_vld[(e + 2) / SC], 0);
        if (!finitef(v.w)) atomicAnd(&s_vld[(e + 3) / SC], 0);
    }

    float4 bc = make_float4(0.f, 0.f, 0.f, 0.f);
    float ar = 0.f;
    int bok = 1;
    if (tid < PREP_ROWS) {
        float4 b = ((const float4*)boxes)[r0 + tid];
        bok = finitef(b.x) && finitef(b.y) && finitef(b.z) && finitef(b.w);
        float w = (float)(*imw), h = (float)(*imh);
        bc.x = fminf(fmaxf(b.x, 0.f), w);
        bc.y = fminf(fmaxf(b.y, 0.f), h);
        bc.z = fminf(fmaxf(b.z, 0.f), w);
        bc.w = fminf(fmaxf(b.w, 0.f), h);
        ar = fmaxf(bc.z - bc.x, 0.f) * fmaxf(bc.w - bc.y, 0.f);
    }
    __syncthreads();
    if (tid < PREP_ROWS) {
        int v = s_vld[tid] && bok;
        s_vld[tid] = v;
        boxes_c[r0 + tid] = bc;
        area[r0 + tid] = v ? ar : -1.0f;
    }
    __syncthreads();

    if (do_t) {
        for (int idx = tid; idx < NCLS * PREP_ROWS; idx += PREP_THREADS) {
            int k = idx >> 5;
            int rr = idx & 31;
            float v = s_sc[rr * SC + k];
            if (!s_vld[rr]) v = -1.0f;
            scores_t[(size_t)k * R + r0 + rr] = v;
        }
    }
}

// ---------------- kernel B: compact + vectorized rank-sort + SoA greedy -----------
#define NMS_THREADS 512
#define KMAX 192
#define PF 512

template <int U>
__device__ __forceinline__ void rank_sort_inplace(unsigned long long* s_key,
                                                  int cnt, int tid) {
    unsigned long long kv[U];
    int rk[U];
#pragma unroll
    for (int m = 0; m < U; ++m) {
        int i = tid + m * NMS_THREADS;
        kv[m] = (i < cnt) ? s_key[i] : 0ull;
        rk[m] = 0;
    }
    {
        const ulonglong2* kp2 = (const ulonglong2*)s_key;
        const int ng = (cnt + 7) >> 3;   // caller padded s_key[cnt..cnt+7] = 0
        for (int g = 0; g < ng; ++g) {
            ulonglong2 a = kp2[g * 4 + 0];
            ulonglong2 b = kp2[g * 4 + 1];
            ulonglong2 c = kp2[g * 4 + 2];
            ulonglong2 d = kp2[g * 4 + 3];
#pragma unroll
            for (int m = 0; m < U; ++m) {
                unsigned long long kk = kv[m];
                rk[m] += (int)(a.x > kk) + (int)(a.y > kk)
                       + (int)(b.x > kk) + (int)(b.y > kk)
                       + (int)(c.x > kk) + (int)(c.y > kk)
                       + (int)(d.x > kk) + (int)(d.y > kk);
            }
        }
    }
    __syncthreads();
#pragma unroll
    for (int m = 0; m < U; ++m) {
        int i = tid + m * NMS_THREADS;
        if (i < cnt) s_key[rk[m]] = kv[m];   // unique keys -> permutation
    }
}

__device__ __forceinline__ void sort_keys(unsigned long long* s_key, int cnt, int tid) {
    if (cnt <= 512) {
        rank_sort_inplace<1>(s_key, cnt, tid);
    } else if (cnt <= 1024) {
        rank_sort_inplace<2>(s_key, cnt, tid);
    } else if (cnt <= 2048) {
        rank_sort_inplace<4>(s_key, cnt, tid);
    } else if (cnt <= 4096) {
        rank_sort_inplace<8>(s_key, cnt, tid);
    } else {
        int npad = 8192;
        for (int i = cnt + tid; i < npad; i += NMS_THREADS) s_key[i] = 0ull;
        __syncthreads();
        for (int kk = 2; kk <= npad; kk <<= 1) {
            for (int j = kk >> 1; j > 0; j >>= 1) {
                for (int i = tid; i < npad; i += NMS_THREADS) {
                    int ixj = i ^ j;
                    if (ixj > i) {
                        unsigned long long a = s_key[i], b = s_key[ixj];
                        bool ascending = ((i & kk) == 0);
                        if ((b > a) == ascending) { s_key[i] = b; s_key[ixj] = a; }
                    }
                }
                __syncthreads();
            }
        }
    }
    __syncthreads();
}

__device__ __forceinline__ float iou_soa(float cx, float cy, float cz, float cw,
                                         float car,
                                         float ox, float oy, float oz, float ow,
                                         float oa) {
    float ltx = fmaxf(cx, ox), lty = fmaxf(cy, oy);
    float rbx = fminf(cz, oz), rby = fminf(cw, ow);
    float iw = fmaxf(rbx - ltx, 0.f), ih = fmaxf(rby - lty, 0.f);
    float inter = iw * ih;
    float uni = car + oa - inter + 1e-9f;
    return inter / uni;
}

__global__ __launch_bounds__(NMS_THREADS) void nms_kernel(
    const float* __restrict__ scores,
    const float* __restrict__ scores_t,
    int use_t,
    const float4* __restrict__ boxes_c,
    const float* __restrict__ area,
    unsigned long long* __restrict__ entries,
    int* __restrict__ ccnt) {
    __shared__ unsigned long long s_key[R + 8];   // 64 KB + pad
    __shared__ float s_cbx[PF], s_cby[PF], s_cbz[PF], s_cbw[PF], s_ca[PF]; // SoA 10 KB
    __shared__ float kbx[KMAX], kby[KMAX], kbz[KMAX], kbw[KMAX], ka[KMAX]; // SoA kept
    __shared__ float sgx[64], sgy[64], sgz[64], sgw[64], sga[64];          // staging
    __shared__ unsigned int s_part[8][64];
    __shared__ unsigned int s_sup1[8][64];
    __shared__ int s_cnt, s_kept;

    const int tid = threadIdx.x;
    const int k = blockIdx.x;
    const int lane = tid & 63;
    const int wv = tid >> 6;

    if (tid == 0) { s_cnt = 0; s_kept = 0; }
    for (int i = tid; i < KMAX; i += NMS_THREADS) {   // zero kept pads for float4 reads
        kbx[i] = 0.f; kby[i] = 0.f; kbz[i] = 0.f; kbw[i] = 0.f; ka[i] = 0.f;
    }
    __syncthreads();

    // ---- compaction (ballot-append; order irrelevant before rank-sort) ----
    if (use_t) {
        const float4* col = (const float4*)(scores_t + (size_t)k * R);
        const unsigned long long ml = (1ull << lane) - 1ull;
        for (int i = tid; i < R / 4; i += NMS_THREADS) {
            float4 v = col[i];
            int r = i * 4;
            bool h0 = v.x > SCORE_THRESH, h1 = v.y > SCORE_THRESH;
            bool h2 = v.z > SCORE_THRESH, h3 = v.w > SCORE_THRESH;
            unsigned long long b0 = __ballot(h0), b1 = __ballot(h1);
            unsigned long long b2 = __ballot(h2), b3 = __ballot(h3);
            int n0 = __popcll(b0);
            int n01 = n0 + __popcll(b1);
            int n012 = n01 + __popcll(b2);
            int tot = n012 + __popcll(b3);
            int base = 0;
            if (lane == 0 && tot) base = atomicAdd(&s_cnt, tot);
            base = __shfl(base, 0);
            if (h0) s_key[base + __popcll(b0 & ml)] = pack_key(v.x, r);
            if (h1) s_key[base + n0 + __popcll(b1 & ml)] = pack_key(v.y, r + 1);
            if (h2) s_key[base + n01 + __popcll(b2 & ml)] = pack_key(v.z, r + 2);
            if (h3) s_key[base + n012 + __popcll(b3 & ml)] = pack_key(v.w, r + 3);
        }
    } else {
        for (int r = tid; r < R; r += NMS_THREADS) {
            float sc = scores[(size_t)r * SC + k];
            if (sc > SCORE_THRESH && area[r] >= 0.f) {
                int p = atomicAdd(&s_cnt, 1);
                s_key[p] = pack_key(sc, r);
            }
        }
    }
    __syncthreads();
    const int cnt = s_cnt;
    if (cnt == 0) {
        if (tid == 0) ccnt[k] = 0;
        return;
    }
    if (tid < 8) s_key[cnt + tid] = 0ull;   // pad for vectorized scan
    __syncthreads();

    sort_keys(s_key, cnt, tid);

    // ---- SoA prefetch of first min(cnt,PF) sorted candidate boxes ----
    const int pfn = cnt < PF ? cnt : PF;
    for (int i = tid; i < pfn; i += NMS_THREADS) {
        int b = 8191 - (int)(s_key[i] & 8191ull);
        float4 cb = boxes_c[b];
        s_cbx[i] = cb.x; s_cby[i] = cb.y; s_cbz[i] = cb.z; s_cbw[i] = cb.w;
        s_ca[i] = fmaxf(cb.z - cb.x, 0.f) * fmaxf(cb.w - cb.y, 0.f);
    }
    __syncthreads();

    // ---- greedy NMS over 64-candidate chunks, 8-wave parallel tests ----
    const int nchunks = (cnt + 63) >> 6;
    for (int c = 0; c < nchunks; ++c) {
        const int kept0 = s_kept;
        if (kept0 >= TOPK_N) break;     // uniform
        const int jbase = c << 6;
        const int j = jbase + lane;
        const bool incand = (j < cnt);
        const bool pf = (jbase < PF);   // chunk fully within prefetch (64 | PF)

        if (!pf) {                      // stage chunk into SoA staging
            if (tid < 64) {
                float4 cb = make_float4(0.f, 0.f, 0.f, 0.f);
                if (incand) {
                    int b = 8191 - (int)(s_key[j] & 8191ull);
                    cb = boxes_c[b];
                }
                sgx[lane] = cb.x; sgy[lane] = cb.y;
                sgz[lane] = cb.z; sgw[lane] = cb.w;
                sga[lane] = fmaxf(cb.z - cb.x, 0.f) * fmaxf(cb.w - cb.y, 0.f);
            }
            __syncthreads();
        }

        const float* BX = pf ? &s_cbx[jbase] : sgx;
        const float* BY = pf ? &s_cby[jbase] : sgy;
        const float* BZ = pf ? &s_cbz[jbase] : sgz;
        const float* BW = pf ? &s_cbw[jbase] : sgw;
        const float* BA = pf ? &s_ca[jbase] : sga;

        float cx = 0.f, cy = 0.f, cz = 0.f, cw = 0.f, car = 0.f;
        if (incand) {
            cx = BX[lane]; cy = BY[lane]; cz = BZ[lane]; cw = BW[lane];
            car = BA[lane];
        }

        {   // kept-list test: wave wv scans a contiguous padded slice, float4 x4
            const int L4 = (((kept0 + 7) >> 3) + 3) & ~3;   // per-wave, mult of 4
            const int t0 = wv * L4;
            unsigned int sup = 0u;
            for (int t = t0; t < t0 + L4; t += 4) {
                float4 xs = *(const float4*)&kbx[t];
                float4 ys = *(const float4*)&kby[t];
                float4 zs = *(const float4*)&kbz[t];
                float4 ws = *(const float4*)&kbw[t];
                float4 as = *(const float4*)&ka[t];
                if (iou_soa(cx, cy, cz, cw, car, xs.x, ys.x, zs.x, ws.x, as.x) > NMS_THRESH) sup = 1u;
                if (iou_soa(cx, cy, cz, cw, car, xs.y, ys.y, zs.y, ws.y, as.y) > NMS_THRESH) sup = 1u;
                if (iou_soa(cx, cy, cz, cw, car, xs.z, ys.z, zs.z, ws.z, as.z) > NMS_THRESH) sup = 1u;
                if (iou_soa(cx, cy, cz, cw, car, xs.w, ys.w, zs.w, ws.w, as.w) > NMS_THRESH) sup = 1u;
            }
            s_sup1[wv][lane] = sup;

            // intra-chunk adjacency: wave wv tests its candidate vs 8 sources
            const int i0 = wv << 3;
            float4 xa = *(const float4*)&BX[i0], xb = *(const float4*)&BX[i0 + 4];
            float4 ya = *(const float4*)&BY[i0], yb = *(const float4*)&BY[i0 + 4];
            float4 za = *(const float4*)&BZ[i0], zb = *(const float4*)&BZ[i0 + 4];
            float4 wa = *(const float4*)&BW[i0], wb = *(const float4*)&BW[i0 + 4];
            float4 aa = *(const float4*)&BA[i0], ab = *(const float4*)&BA[i0 + 4];
            float X[8] = {xa.x, xa.y, xa.z, xa.w, xb.x, xb.y, xb.z, xb.w};
            float Y[8] = {ya.x, ya.y, ya.z, ya.w, yb.x, yb.y, yb.z, yb.w};
            float Z[8] = {za.x, za.y, za.z, za.w, zb.x, zb.y, zb.z, zb.w};
            float W[8] = {wa.x, wa.y, wa.z, wa.w, wb.x, wb.y, wb.z, wb.w};
            float A[8] = {aa.x, aa.y, aa.z, aa.w, ab.x, ab.y, ab.z, ab.w};
            unsigned int pm = 0u;
#pragma unroll
            for (int ii = 0; ii < 8; ++ii) {
                int i = i0 + ii;
                if (i != lane &&
                    iou_soa(cx, cy, cz, cw, car, X[ii], Y[ii], Z[ii], W[ii], A[ii]) > NMS_THRESH)
                    pm |= 1u << ii;
            }
            s_part[wv][lane] = pm;
        }
        __syncthreads();

        if (tid < 64) {   // wave 0: bitmask greedy resolve
            unsigned int sup1u = 0u;
            unsigned long long supmask = 0ull;
#pragma unroll
            for (int w2 = 0; w2 < 8; ++w2) {
                sup1u |= s_sup1[w2][lane];
                supmask |= (unsigned long long)s_part[w2][lane] << (w2 * 8);
            }
            bool alive0 = incand && !sup1u;
            unsigned long long av = __ballot(alive0);
            unsigned long long kept = 0ull;
#pragma unroll
            for (int l2 = 0; l2 < 64; ++l2) {
                unsigned long long m = __shfl(supmask, l2);   // indep of `kept`
                if (((av >> l2) & 1ull) && !(m & kept)) kept |= 1ull << l2;
            }
            if ((kept >> lane) & 1ull) {
                int pos = kept0 + (int)__popcll(kept & ((1ull << lane) - 1ull));
                if (pos < KMAX) {
                    kbx[pos] = cx; kby[pos] = cy; kbz[pos] = cz; kbw[pos] = cw;
                    ka[pos] = car;
                }
                if (pos < TOPK_N) {
                    unsigned long long kv = s_key[j];
                    int bidx = 8191 - (int)(kv & 8191ull);
                    entries[k * TOPK_N + pos] =
                        ((unsigned long long)(unsigned int)(k * R + bidx) << 32) |
                        (kv >> 13);
                }
            }
            if (lane == 0) s_kept = kept0 + (int)__popcll(kept);
        }
        __syncthreads();
    }

    if (tid == 0) {
        int kf = s_kept;
        ccnt[k] = kf < TOPK_N ? kf : TOPK_N;
    }
}

// ------- kernel C: low-latency topk — 1 histogram + candidate collect + n2 rank ----
#define TK_THREADS 512
#define CAND_CAP 1024

__global__ __launch_bounds__(TK_THREADS) void topk_kernel(
    const unsigned long long* __restrict__ entries,
    const int* __restrict__ ccnt,
    const float4* __restrict__ boxes_c,
    float* __restrict__ out) {
    __shared__ uint4 s_keys4[NENT / 4];       // 32000 B: all 8000 score keys
    __shared__ unsigned int hist[4096];       // 16384 B
    __shared__ unsigned int ckd[CAND_CAP];    // candidate keys
    __shared__ int          cpd[CAND_CAP];    // candidate positions
    __shared__ unsigned int fkey[TOPK_N];
    __shared__ int          fpos[TOPK_N];
    __shared__ unsigned int s_wsum[8];
    __shared__ unsigned int s_bin, s_gt;      // target bin, count strictly above
    __shared__ unsigned int s_c2bin;          // refine-level bin (if used)
    __shared__ int s_refine;
    __shared__ unsigned int a_c;
    __shared__ int s_M;

    const int tid = threadIdx.x;
    const int wv = tid >> 6, lane = tid & 63;
    unsigned int* s_keys = (unsigned int*)s_keys4;
    const unsigned int* e32 = (const unsigned int*)entries;

    // ---- coalesced: entries low words -> LDS ----
    {
        const ulonglong2* e2 = (const ulonglong2*)entries;
        for (int idx = tid; idx < NENT / 2; idx += TK_THREADS) {
            ulonglong2 v = e2[idx];
            s_keys[2 * idx + 0] = (unsigned int)v.x;
            s_keys[2 * idx + 1] = (unsigned int)v.y;
        }
    }
    if (tid == 0) { s_M = 0; a_c = 0u; s_refine = 0; s_bin = 0u; s_gt = 0u; s_c2bin = 0u; }
    if (tid < TOPK_N) { fkey[tid] = 0u; fpos[tid] = 0; }
    __syncthreads();
    if (tid < NCLS) atomicAdd(&s_M, ccnt[tid]);   // ccnt already capped at 100
    for (int j = tid; j < 4096; j += TK_THREADS) hist[j] = 0u;
    __syncthreads();
    const int M = s_M;

    if (M >= TOPK_N) {
        // ---- level-1 histogram: bits 25..14 (keys in (0.05,1]: bits 31..26 fixed)
#pragma unroll
        for (int i = 0; i < 4; ++i) {
            int idx4 = i * TK_THREADS + tid;
            if (idx4 < NENT / 4) {
                uint4 kv4 = s_keys4[idx4];
                if (kv4.x) atomicAdd(&hist[(kv4.x >> 14) & 4095u], 1u);
                if (kv4.y) atomicAdd(&hist[(kv4.y >> 14) & 4095u], 1u);
                if (kv4.z) atomicAdd(&hist[(kv4.z >> 14) & 4095u], 1u);
                if (kv4.w) atomicAdd(&hist[(kv4.w >> 14) & 4095u], 1u);
            }
        }
        __syncthreads();
        // ---- suffix scan (8 bins per thread, 8-wave) -> find rank-100 bin ----
        {
            unsigned int g = 0u;
#pragma unroll
            for (int b = 0; b < 8; ++b) g += hist[tid * 8 + b];
            unsigned int S = g;
            for (int off = 1; off < 64; off <<= 1) {
                unsigned int v = __shfl_down(S, off);
                if (lane + off < 64) S += v;
            }
            if (lane == 0) s_wsum[wv] = S;
            __syncthreads();
            unsigned int above_w = 0u;
            for (int w2 = wv + 1; w2 < 8; ++w2) above_w += s_wsum[w2];
            unsigned int Sown = S + above_w;
            unsigned int above = Sown - g;
            if (above < TOPK_N && TOPK_N <= Sown) {   // exactly one thread
                unsigned int cum = above;
                for (int b = 7; b >= 0; --b) {
                    int bin = tid * 8 + b;
                    unsigned int tb = hist[bin];
                    cum += tb;
                    if (cum >= TOPK_N) {
                        s_bin = (unsigned int)bin;
                        s_gt = cum - tb;                    // strictly above this bin
                        if (cum > CAND_CAP) s_refine = 1;   // too many candidates
                        break;
                    }
                }
            }
        }
        __syncthreads();

        if (s_refine) {
            // ---- level-2: refine within target bin on bits 13..2 ----
            for (int j = tid; j < 4096; j += TK_THREADS) hist[j] = 0u;
            __syncthreads();
            const unsigned int B = s_bin;
#pragma unroll
            for (int i = 0; i < 4; ++i) {
                int idx4 = i * TK_THREADS + tid;
                if (idx4 < NENT / 4) {
                    uint4 kv4 = s_keys4[idx4];
                    unsigned int kvs[4] = {kv4.x, kv4.y, kv4.z, kv4.w};
#pragma unroll
                    for (int c = 0; c < 4; ++c) {
                        unsigned int kv = kvs[c];
                        if (kv && ((kv >> 14) & 4095u) == B)
                            atomicAdd(&hist[(kv >> 2) & 4095u], 1u);
                    }
                }
            }
            __syncthreads();
            const unsigned int r2 = TOPK_N - s_gt;   // rank needed inside bin B
            unsigned int g = 0u;
#pragma unroll
            for (int b = 0; b < 8; ++b) g += hist[tid * 8 + b];
            unsigned int S = g;
            for (int off = 1; off < 64; off <<= 1) {
                unsigned int v = __shfl_down(S, off);
                if (lane + off < 64) S += v;
            }
            if (lane == 0) s_wsum[wv] = S;
            __syncthreads();
            unsigned int above_w = 0u;
            for (int w2 = wv + 1; w2 < 8; ++w2) above_w += s_wsum[w2];
            unsigned int Sown = S + above_w;
            unsigned int above = Sown - g;
            if (above < r2 && r2 <= Sown) {
                unsigned int cum = above;
                for (int b = 7; b >= 0; --b) {
                    int bin = tid * 8 + b;
                    unsigned int tb = hist[bin];
                    cum += tb;
                    if (cum >= r2) { s_c2bin = (unsigned int)bin; break; }
                }
            }
            __syncthreads();
        }
    }
    __syncthreads();

    // ---- collect candidates: everything that could be in the top-100 ----
    const unsigned int B1 = s_bin;
    const unsigned int B2 = s_c2bin;
    const int refine = s_refine;
#pragma unroll
    for (int i = 0; i < 4; ++i) {
        int idx4 = i * TK_THREADS + tid;
        if (idx4 < NENT / 4) {
            uint4 kv4 = s_keys4[idx4];
            unsigned int kvs[4] = {kv4.x, kv4.y, kv4.z, kv4.w};
#pragma unroll
            for (int c = 0; c < 4; ++c) {
                unsigned int kv = kvs[c];
                if (!kv) continue;
                bool cand;
                if (M < TOPK_N) {
                    cand = true;                       // take all real entries
                } else {
                    unsigned int b1 = (kv >> 14) & 4095u;
                    if (b1 > B1) cand = true;
                    else if (b1 < B1) cand = false;
                    else if (!refine) cand = true;     // whole target bin
                    else cand = (((kv >> 2) & 4095u) >= B2);
                }
                if (cand) {
                    unsigned int p = atomicAdd(&a_c, 1u);
                    if (p < CAND_CAP) { ckd[p] = kv; cpd[p] = 4 * idx4 + c; }
                }
            }
        }
    }
    __syncthreads();

    // ---- n^2 rank of candidates: (key desc, pos asc); keep ranks < 100 ----
    const int cn = (int)(a_c < CAND_CAP ? a_c : CAND_CAP);
    if (tid < cn) {
        unsigned int kk = ckd[tid];
        int pp = cpd[tid];
        unsigned int rnk = 0u;
        for (int j = 0; j < cn; ++j) {
            unsigned int kj = ckd[j];
            int pj = cpd[j];
            rnk += (kj > kk) || (kj == kk && pj < pp);
        }
        if (rnk < TOPK_N) { fkey[rnk] = kk; fpos[rnk] = pp; }
    }
    __syncthreads();

    // ---- emit ----
    const int SELN = (M >= TOPK_N) ? TOPK_N : M;
    if (tid < TOPK_N) {
        bool dv = (tid < SELN);
        int pos = fpos[tid];
        float s = __uint_as_float(fkey[tid]);
        int flat = dv ? (int)e32[2 * pos + 1] : 0;
        int r = flat & (R - 1);
        int kc = flat >> 13;
        float4 bb = dv ? boxes_c[r] : make_float4(0.f, 0.f, 0.f, 0.f);
        out[tid * 4 + 0] = bb.x;
        out[tid * 4 + 1] = bb.y;
        out[tid * 4 + 2] = bb.z;
        out[tid * 4 + 3] = bb.w;
        out[400 + tid] = dv ? s : 0.f;
        out[500 + tid] = dv ? (float)kc : -1.f;
        out[600 + tid] = dv ? (float)r : -1.f;
    }
}

extern "C" void kernel_launch(void* const* d_in, const int* in_sizes, int n_in,
                              void* d_out, int out_size, void* d_ws, size_t ws_size,
                              hipStream_t stream) {
    const float* boxes  = (const float*)d_in[0];
    const float* scores = (const float*)d_in[1];
    const int*   imh    = (const int*)d_in[2];
    const int*   imw    = (const int*)d_in[3];

    char* ws = (char*)d_ws;
    float4*             boxes_c  = (float4*)(ws + BOXC_OFF);
    float*              area     = (float*)(ws + AREA_OFF);
    unsigned long long* entries  = (unsigned long long*)(ws + ENT_OFF);
    int*                ccnt     = (int*)(ws + CCNT_OFF);
    float*              scores_t = (float*)(ws + ST_OFF);

    const size_t needed_t = (size_t)ST_OFF + (size_t)NCLS * R * sizeof(float);
    const int use_t = (ws_size >= needed_t) ? 1 : 0;

    prep_kernel<<<R / PREP_ROWS, PREP_THREADS, 0, stream>>>(
        boxes, scores, imh, imw, boxes_c, area, entries, scores_t, use_t);
    nms_kernel<<<NCLS, NMS_THREADS, 0, stream>>>(
        scores, scores_t, use_t, boxes_c, area, entries, ccnt);
    topk_kernel<<<1, TK_THREADS, 0, stream>>>(entries, ccnt, boxes_c,
                                              (float*)d_out);
}